// Round 2
// baseline (15135.585 us; speedup 1.0000x reference)
//
#include <hip/hip_runtime.h>
#include <cmath>

#define TT 1024
#define BB 256

__device__ __forceinline__ float fast_rcp(float x) { return __builtin_amdgcn_rcpf(x); }
__device__ __forceinline__ float fast_sigmoid(float x) { return fast_rcp(1.0f + __expf(-x)); }
__device__ __forceinline__ float fast_tanh(float x) {
    // tanh(x) = 1 - 2/(exp(2x)+1); saturates correctly: exp->inf => 1, exp->0 => -1
    return 1.0f - 2.0f * fast_rcp(1.0f + __expf(2.0f * x));
}

// One block per batch element. Thread j owns gate row j (j in [0,4H)).
// Weight rows in registers (float4), h/x broadcast via uniform-address
// ds_read_b128 from LDS, x double-buffered and prefetched one step ahead,
// activations distributed across all 4H threads.
template<int H, int I>
__global__ __launch_bounds__(4*H, 2) void lstm_layer(
    const float* __restrict__ x,     // [B, T, I]
    const float* __restrict__ Wih,   // [4H, I]
    const float* __restrict__ Whh,   // [4H, H]
    const float* __restrict__ bias,  // [4H]
    const float* __restrict__ h0,    // [B, H] or nullptr (-> zeros)
    const float* __restrict__ c0,    // [B, H] or nullptr
    float* __restrict__ out)         // [B, T, H]
{
    constexpr int FH = 4 * H;
    constexpr int I4 = I / 4;        // I in {100,32,64}: all /4
    constexpr int H4 = H / 4;
    const int b = blockIdx.x;
    const int j = threadIdx.x;       // 0..4H-1

    // --- weight rows into registers (float4, fully unrolled -> SROA) ---
    float4 wih[I4];
    float4 whh[H4];
    {
        const float4* Wih4 = reinterpret_cast<const float4*>(Wih + (size_t)j * I);
        const float4* Whh4 = reinterpret_cast<const float4*>(Whh + (size_t)j * H);
        #pragma unroll
        for (int k = 0; k < I4; ++k) wih[k] = Wih4[k];
        #pragma unroll
        for (int k = 0; k < H4; ++k) whh[k] = Whh4[k];
    }
    const float bj = bias[j];

    __shared__ alignas(16) float x_lds[2][I];
    __shared__ alignas(16) float h_lds[H];
    __shared__ float act_lds[FH];

    const float* xb = x + (size_t)b * TT * I;
    float*       ob = out + (size_t)b * TT * H;

    // --- init state + stage x_0 ---
    float c = 0.0f;
    if (j < H) {
        h_lds[j] = (h0 != nullptr) ? h0[b * H + j] : 0.0f;
        if (c0 != nullptr) c = c0[b * H + j];
    }
    if (j < I) x_lds[0][j] = xb[j];
    __syncthreads();

    for (int t = 0; t < TT; ++t) {
        // issue prefetch of x_{t+1}; latency hides under GEMV
        float xn = 0.0f;
        if (t + 1 < TT && j < I) xn = xb[(size_t)(t + 1) * I + j];

        // g[j] = b[j] + dot(x_t, Wih[j,:]) + dot(h_{t-1}, Whh[j,:])
        float4 a = make_float4(bj, 0.0f, 0.0f, 0.0f);
        const float4* xl = reinterpret_cast<const float4*>(x_lds[t & 1]);
        #pragma unroll
        for (int k = 0; k < I4; ++k) {
            float4 v = xl[k];                 // uniform addr -> broadcast b128
            a.x = fmaf(v.x, wih[k].x, a.x);
            a.y = fmaf(v.y, wih[k].y, a.y);
            a.z = fmaf(v.z, wih[k].z, a.z);
            a.w = fmaf(v.w, wih[k].w, a.w);
        }
        const float4* hl = reinterpret_cast<const float4*>(h_lds);
        #pragma unroll
        for (int k = 0; k < H4; ++k) {
            float4 v = hl[k];
            a.x = fmaf(v.x, whh[k].x, a.x);
            a.y = fmaf(v.y, whh[k].y, a.y);
            a.z = fmaf(v.z, whh[k].z, a.z);
            a.w = fmaf(v.w, whh[k].w, a.w);
        }
        float g = (a.x + a.y) + (a.z + a.w);

        // stage x_{t+1} into the other buffer (safe: its last readers
        // finished before this iteration's entry barrier)
        if (t + 1 < TT && j < I) x_lds[(t + 1) & 1][j] = xn;

        // distributed activation: thread j activates its own gate row
        // rows [0,H)=i(sig), [H,2H)=f(sig), [2H,3H)=g(tanh), [3H,4H)=o(sig)
        float act = (j >= 2 * H && j < 3 * H) ? fast_tanh(g) : fast_sigmoid(g);
        act_lds[j] = act;
        __syncthreads();                      // bar A: acts + x_{t+1} staged

        if (j < H) {
            float ai = act_lds[j];
            float af = act_lds[H + j];
            float ag = act_lds[2 * H + j];
            float ao = act_lds[3 * H + j];
            c = fmaf(af, c, ai * ag);
            float h = ao * fast_tanh(c);
            h_lds[j] = h;
            ob[(size_t)t * H + j] = h;
        }
        __syncthreads();                      // bar B: h_t visible
    }
}

// out[bt] = tanh(dot(r[bt,:128], Wl) + bl)
__global__ __launch_bounds__(256) void final_proj(
    const float* __restrict__ r,   // [B*T, 128]
    const float* __restrict__ Wl,  // [128]
    const float* __restrict__ bl,  // [1]
    float* __restrict__ out)       // [B*T]
{
    __shared__ float wl[128];
    const int tid = threadIdx.x;
    if (tid < 128) wl[tid] = Wl[tid];
    __syncthreads();

    const int bt = blockIdx.x * 256 + tid;
    const float4* rr = reinterpret_cast<const float4*>(r + (size_t)bt * 128);
    float a0 = 0.f, a1 = 0.f, a2 = 0.f, a3 = 0.f;
    #pragma unroll
    for (int k = 0; k < 32; ++k) {
        float4 v = rr[k];
        a0 = fmaf(v.x, wl[4 * k + 0], a0);
        a1 = fmaf(v.y, wl[4 * k + 1], a1);
        a2 = fmaf(v.z, wl[4 * k + 2], a2);
        a3 = fmaf(v.w, wl[4 * k + 3], a3);
    }
    out[bt] = tanhf(((a0 + a1) + (a2 + a3)) + bl[0]);
}

extern "C" void kernel_launch(void* const* d_in, const int* in_sizes, int n_in,
                              void* d_out, int out_size, void* d_ws, size_t ws_size,
                              hipStream_t stream) {
    const float* input = (const float*)d_in[0];
    const float* h_0   = (const float*)d_in[1];   // [1,B,32]
    const float* c_0   = (const float*)d_in[2];
    const float* Wih0  = (const float*)d_in[3];
    const float* Whh0  = (const float*)d_in[4];
    const float* b0    = (const float*)d_in[5];
    const float* Wih1  = (const float*)d_in[6];
    const float* Whh1  = (const float*)d_in[7];
    const float* b1    = (const float*)d_in[8];
    const float* Wih2  = (const float*)d_in[9];
    const float* Whh2  = (const float*)d_in[10];
    const float* b2    = (const float*)d_in[11];
    const float* Wl    = (const float*)d_in[12];
    const float* bl    = (const float*)d_in[13];

    float* out = (float*)d_out;                       // [B*T] = 262144 floats
    float* r2  = out + (size_t)BB * TT;               // [B,T,128] (2nd output)
    float* r0  = (float*)d_ws;                        // [B,T,32]
    float* r1  = r0 + (size_t)BB * TT * 32;           // [B,T,64]

    hipLaunchKernelGGL((lstm_layer<32, 100>), dim3(BB), dim3(128), 0, stream,
                       input, Wih0, Whh0, b0, h_0, c_0, r0);
    hipLaunchKernelGGL((lstm_layer<64, 32>),  dim3(BB), dim3(256), 0, stream,
                       r0, Wih1, Whh1, b1, nullptr, nullptr, r1);
    hipLaunchKernelGGL((lstm_layer<128, 64>), dim3(BB), dim3(512), 0, stream,
                       r1, Wih2, Whh2, b2, nullptr, nullptr, r2);
    hipLaunchKernelGGL(final_proj, dim3(BB * TT / 256), dim3(256), 0, stream,
                       r2, Wl, bl, out);
}

// Round 3
// 2758.698 us; speedup vs baseline: 5.4865x; 5.4865x over previous
//
#include <hip/hip_runtime.h>
#include <cmath>

#define TT 1024
#define BB 256

__device__ __forceinline__ float fast_rcp(float x) { return __builtin_amdgcn_rcpf(x); }
__device__ __forceinline__ float fast_sigmoid(float x) { return fast_rcp(1.0f + __expf(-x)); }
__device__ __forceinline__ float fast_tanh(float x) {
    // tanh(x) = 1 - 2/(exp(2x)+1); saturates correctly at +-inf
    return 1.0f - 2.0f * fast_rcp(1.0f + __expf(2.0f * x));
}

// One block per batch element. Gate row j's dot product over the concatenated
// [x_t | h_t] vector (K = I+H) is split across NS threads; thread (s,j) holds
// weight slice [s*P, s*P+P) in registers (P/4 float4 -> small enough that the
// register allocator keeps it: L2 ~118 VGPR < 128 cap, L1 ~42, L0 ~55).
// Partials reduced via LDS; 2 barriers/step; x prefetched one step ahead.
template<int H, int I, int NS>
__global__ __launch_bounds__(NS * 4 * H) void lstm_layer(
    const float* __restrict__ x,     // [B, T, I]
    const float* __restrict__ Wih,   // [4H, I]
    const float* __restrict__ Whh,   // [4H, H]
    const float* __restrict__ bias,  // [4H]
    const float* __restrict__ h0,    // [B, H] or nullptr (-> zeros)
    const float* __restrict__ c0,    // [B, H] or nullptr
    float* __restrict__ out)         // [B, T, H]
{
    constexpr int FH = 4 * H;
    constexpr int K  = I + H;
    constexpr int P  = (((K + NS - 1) / NS + 3) / 4) * 4;  // slice floats, /4
    constexpr int N4 = P / 4;                              // float4 per thread
    constexpr int XL = NS * P;                             // padded [x|h] length
    const int tid = threadIdx.x;
    const int s   = tid / FH;        // wave-uniform: FH is a multiple of 64
    const int j   = tid & (FH - 1);  // gate row

    // --- weight slice into registers (once; unrolled constant indices) ---
    float4 w[N4];
    {
        const int base = s * P;
        #pragma unroll
        for (int k4 = 0; k4 < N4; ++k4) {
            float tmp[4];
            #pragma unroll
            for (int u = 0; u < 4; ++u) {
                const int e = base + k4 * 4 + u;
                float v = 0.0f;
                if (e < I)      v = Wih[(size_t)j * I + e];
                else if (e < K) v = Whh[(size_t)j * H + (e - I)];
                tmp[u] = v;
            }
            w[k4] = make_float4(tmp[0], tmp[1], tmp[2], tmp[3]);
        }
    }

    __shared__ alignas(16) float xh[2][XL];   // [x (I) | h (H) | zero pad]
    __shared__ float plds[NS * FH];

    const int b = blockIdx.x;
    const float* xb = x + (size_t)b * TT * I;
    float*       ob = out + (size_t)b * TT * H;

    // --- init: zero tail pad (both buffers), stage x_0, h_0, c ---
    if (tid < XL - K) { xh[0][K + tid] = 0.0f; xh[1][K + tid] = 0.0f; }
    if (tid < I) xh[0][tid] = xb[tid];
    float c = 0.0f;
    float br0 = 0.f, br1 = 0.f, br2 = 0.f, br3 = 0.f;
    if (tid < H) {
        xh[0][I + tid] = (h0 != nullptr) ? h0[b * H + tid] : 0.0f;
        if (c0 != nullptr) c = c0[b * H + tid];
        br0 = bias[tid];
        br1 = bias[H + tid];
        br2 = bias[2 * H + tid];
        br3 = bias[3 * H + tid];
    }
    __syncthreads();

    for (int t = 0; t < TT; ++t) {
        // prefetch x_{t+1} (latency hides under GEMV below)
        float xn = 0.0f;
        const bool stager = (s == 1) && (j < I);
        if (stager && t + 1 < TT) xn = xb[(size_t)(t + 1) * I + j];

        // partial dot over this thread's K-slice (broadcast ds_read_b128)
        const float4* xv = reinterpret_cast<const float4*>(&xh[t & 1][s * P]);
        float4 a = make_float4(0.f, 0.f, 0.f, 0.f);
        #pragma unroll
        for (int k4 = 0; k4 < N4; ++k4) {
            float4 v = xv[k4];
            a.x = fmaf(v.x, w[k4].x, a.x);
            a.y = fmaf(v.y, w[k4].y, a.y);
            a.z = fmaf(v.z, w[k4].z, a.z);
            a.w = fmaf(v.w, w[k4].w, a.w);
        }
        plds[tid] = (a.x + a.y) + (a.z + a.w);
        __syncthreads();                       // bar1: partials ready

        // stage x_{t+1} into the other buffer (its last readers finished
        // before the previous bar1)
        if (stager && t + 1 < TT) xh[(t + 1) & 1][j] = xn;

        if (tid < H) {
            float g0 = br0, g1 = br1, g2 = br2, g3 = br3;
            #pragma unroll
            for (int n = 0; n < NS; ++n) {
                g0 += plds[n * FH + tid];
                g1 += plds[n * FH + H + tid];
                g2 += plds[n * FH + 2 * H + tid];
                g3 += plds[n * FH + 3 * H + tid];
            }
            float ai = fast_sigmoid(g0);
            float af = fast_sigmoid(g1);
            float ag = fast_tanh(g2);
            float ao = fast_sigmoid(g3);
            c = fmaf(af, c, ai * ag);
            float h = ao * fast_tanh(c);
            xh[(t + 1) & 1][I + tid] = h;      // next step's h
            ob[(size_t)t * H + tid] = h;
        }
        __syncthreads();                       // bar2: next xh fully staged
    }
}

// out[bt] = tanh(dot(r[bt,:128], Wl) + bl)
__global__ __launch_bounds__(256) void final_proj(
    const float* __restrict__ r,   // [B*T, 128]
    const float* __restrict__ Wl,  // [128]
    const float* __restrict__ bl,  // [1]
    float* __restrict__ out)       // [B*T]
{
    __shared__ float wl[128];
    const int tid = threadIdx.x;
    if (tid < 128) wl[tid] = Wl[tid];
    __syncthreads();

    const int bt = blockIdx.x * 256 + tid;
    const float4* rr = reinterpret_cast<const float4*>(r + (size_t)bt * 128);
    float a0 = 0.f, a1 = 0.f, a2 = 0.f, a3 = 0.f;
    #pragma unroll
    for (int k = 0; k < 32; ++k) {
        float4 v = rr[k];
        a0 = fmaf(v.x, wl[4 * k + 0], a0);
        a1 = fmaf(v.y, wl[4 * k + 1], a1);
        a2 = fmaf(v.z, wl[4 * k + 2], a2);
        a3 = fmaf(v.w, wl[4 * k + 3], a3);
    }
    out[bt] = tanhf(((a0 + a1) + (a2 + a3)) + bl[0]);
}

extern "C" void kernel_launch(void* const* d_in, const int* in_sizes, int n_in,
                              void* d_out, int out_size, void* d_ws, size_t ws_size,
                              hipStream_t stream) {
    const float* input = (const float*)d_in[0];
    const float* h_0   = (const float*)d_in[1];   // [1,B,32]
    const float* c_0   = (const float*)d_in[2];
    const float* Wih0  = (const float*)d_in[3];
    const float* Whh0  = (const float*)d_in[4];
    const float* b0    = (const float*)d_in[5];
    const float* Wih1  = (const float*)d_in[6];
    const float* Whh1  = (const float*)d_in[7];
    const float* b1    = (const float*)d_in[8];
    const float* Wih2  = (const float*)d_in[9];
    const float* Whh2  = (const float*)d_in[10];
    const float* b2    = (const float*)d_in[11];
    const float* Wl    = (const float*)d_in[12];
    const float* bl    = (const float*)d_in[13];

    float* out = (float*)d_out;                       // [B*T]
    float* r2  = out + (size_t)BB * TT;               // [B,T,128] (2nd output)
    float* r0  = (float*)d_ws;                        // [B,T,32]
    float* r1  = r0 + (size_t)BB * TT * 32;           // [B,T,64]

    // L0: K=132, NS=4 -> block 512, P=36 (~55 VGPR)
    hipLaunchKernelGGL((lstm_layer<32, 100, 4>), dim3(BB), dim3(512), 0, stream,
                       input, Wih0, Whh0, b0, h_0, c_0, r0);
    // L1: K=96, NS=4 -> block 1024, P=24 (~42 VGPR)
    hipLaunchKernelGGL((lstm_layer<64, 32, 4>),  dim3(BB), dim3(1024), 0, stream,
                       r0, Wih1, Whh1, b1, nullptr, nullptr, r1);
    // L2: K=192, NS=2 -> block 1024, P=96 (~118 VGPR, must stay <=128)
    hipLaunchKernelGGL((lstm_layer<128, 64, 2>), dim3(BB), dim3(1024), 0, stream,
                       r1, Wih2, Whh2, b2, nullptr, nullptr, r2);
    hipLaunchKernelGGL(final_proj, dim3(BB * TT / 256), dim3(256), 0, stream,
                       r2, Wl, bl, out);
}

// Round 4
// 2577.760 us; speedup vs baseline: 5.8716x; 1.0702x over previous
//
#include <hip/hip_runtime.h>
#include <cmath>

#define TT 1024
#define BB 256

__device__ __forceinline__ float fast_rcp(float x) { return __builtin_amdgcn_rcpf(x); }
__device__ __forceinline__ float fast_sigmoid(float x) { return fast_rcp(1.0f + __expf(-x)); }
__device__ __forceinline__ float fast_tanh(float x) {
    // tanh(x) = 1 - 2/(exp(2x)+1); saturates correctly at +-inf
    return 1.0f - 2.0f * fast_rcp(1.0f + __expf(2.0f * x));
}

// ============================================================================
// Kernel A: fused LSTM layers 0+1, one block per batch element, L1 lagged one
// step so both layers' GEMVs and activation tails run concurrently.
//   L0: H=32, in=100 (K0=132, padded 144), rows=128, NS=4 -> tid [0,512), P=36
//   L1: H=64, in=32  (K1=96),             rows=256, NS=2 -> tid [512,1024), P=48
// Finishers: L0 state tid [0,32); L1 state tid [64,128); x stagers tid [128,228).
// 2 barriers per mega-step. r0 (h0 stream) never leaves LDS.
// ============================================================================
__global__ __attribute__((amdgpu_flat_work_group_size(1024, 1024)))
           __attribute__((amdgpu_waves_per_eu(4, 4)))
void lstm01_fused(const float* __restrict__ x,      // [B, T, 100]
                  const float* __restrict__ Wih0,   // [128, 100]
                  const float* __restrict__ Whh0,   // [128, 32]
                  const float* __restrict__ b0,     // [128]
                  const float* __restrict__ Wih1,   // [256, 32]
                  const float* __restrict__ Whh1,   // [256, 64]
                  const float* __restrict__ b1,     // [256]
                  const float* __restrict__ h_0,    // [1, B, 32]
                  const float* __restrict__ c_0,    // [1, B, 32]
                  float* __restrict__ r1)           // [B, T, 64]
{
    const int b   = blockIdx.x;
    const int tid = threadIdx.x;
    const bool isL0 = (tid < 512);
    const int s0 = (tid >> 7) & 3, j0 = tid & 127;          // L0 slice/row
    const int s1 = (tid >> 8) & 1, j1 = tid & 255;          // L1 slice/row (tid>=512)

    // --- weight slice into registers (shared 12-float4 array, role-overlaid) ---
    float4 w[12];
    if (isL0) {
        #pragma unroll
        for (int k4 = 0; k4 < 9; ++k4) {
            float tv[4];
            #pragma unroll
            for (int u = 0; u < 4; ++u) {
                const int e = s0 * 36 + k4 * 4 + u;
                tv[u] = (e < 100) ? Wih0[(size_t)j0 * 100 + e]
                      : (e < 132) ? Whh0[(size_t)j0 * 32 + (e - 100)] : 0.0f;
            }
            w[k4] = make_float4(tv[0], tv[1], tv[2], tv[3]);
        }
        #pragma unroll
        for (int k4 = 9; k4 < 12; ++k4) w[k4] = make_float4(0.f, 0.f, 0.f, 0.f);
    } else {
        #pragma unroll
        for (int k4 = 0; k4 < 12; ++k4) {
            float tv[4];
            #pragma unroll
            for (int u = 0; u < 4; ++u) {
                const int e = s1 * 48 + k4 * 4 + u;
                tv[u] = (e < 32) ? Wih1[(size_t)j1 * 32 + e]
                                 : Whh1[(size_t)j1 * 64 + (e - 32)];
            }
            w[k4] = make_float4(tv[0], tv[1], tv[2], tv[3]);
        }
    }

    __shared__ alignas(16) float xh0[2][144];   // [x(100) | h0(32) | pad(12)=0]
    __shared__ alignas(16) float xh1[2][96];    // [h0(32) | h1(64)]
    __shared__ float plds[1024];                // L0 partials [0,512), L1 [512,1024)

    const float* xb = x + (size_t)b * TT * 100;

    // --- init ---
    float c0v = 0.f, c1v = 0.f;
    float bi0 = 0.f, bf0 = 0.f, bg0 = 0.f, bo0 = 0.f;
    float bi1 = 0.f, bf1 = 0.f, bg1 = 0.f, bo1 = 0.f;
    if (tid < 100) xh0[0][tid] = xb[tid];
    if (tid < 32) {
        xh0[0][100 + tid] = h_0[b * 32 + tid];
        c0v = c_0[b * 32 + tid];
        bi0 = b0[tid]; bf0 = b0[32 + tid]; bg0 = b0[64 + tid]; bo0 = b0[96 + tid];
    }
    if (tid >= 132 && tid < 144) { xh0[0][tid] = 0.f; xh0[1][tid] = 0.f; }  // pads
    if (tid < 96) { xh1[0][tid] = 0.f; xh1[1][tid] = 0.f; }                 // h0|h1 zero
    if (tid >= 64 && tid < 128) {
        const int j = tid - 64;
        bi1 = b1[j]; bf1 = b1[64 + j]; bg1 = b1[128 + j]; bo1 = b1[192 + j];
    }
    const bool stager = (tid >= 128 && tid < 228);
    __syncthreads();

    for (int m = 0; m <= TT; ++m) {
        const int cur = m & 1, nxt = cur ^ 1;

        // ---- phase A: prefetch + both GEMVs ----
        float xn = 0.f;
        if (stager && m + 1 < TT) xn = xb[(size_t)(m + 1) * 100 + (tid - 128)];

        const bool doG = isL0 ? (m < TT) : (m >= 1);
        if (doG) {
            float4 a = make_float4(0.f, 0.f, 0.f, 0.f);
            if (isL0) {
                const float4* v4 = reinterpret_cast<const float4*>(&xh0[cur][s0 * 36]);
                #pragma unroll
                for (int k = 0; k < 9; ++k) {
                    float4 v = v4[k];
                    a.x = fmaf(v.x, w[k].x, a.x); a.y = fmaf(v.y, w[k].y, a.y);
                    a.z = fmaf(v.z, w[k].z, a.z); a.w = fmaf(v.w, w[k].w, a.w);
                }
            } else {
                const float4* v4 = reinterpret_cast<const float4*>(&xh1[cur][s1 * 48]);
                #pragma unroll
                for (int k = 0; k < 12; ++k) {
                    float4 v = v4[k];
                    a.x = fmaf(v.x, w[k].x, a.x); a.y = fmaf(v.y, w[k].y, a.y);
                    a.z = fmaf(v.z, w[k].z, a.z); a.w = fmaf(v.w, w[k].w, a.w);
                }
            }
            plds[tid] = (a.x + a.y) + (a.z + a.w);
        }
        __syncthreads();   // bar1: partials ready

        // ---- phase B: state updates + staging ----
        if (tid < 32 && m < TT) {           // L0 finish (rows tid,32+,64+,96+; 4 slices)
            float gi = bi0, gf = bf0, gg = bg0, go = bo0;
            #pragma unroll
            for (int s = 0; s < 4; ++s) {
                gi += plds[s * 128 + tid];
                gf += plds[s * 128 + 32 + tid];
                gg += plds[s * 128 + 64 + tid];
                go += plds[s * 128 + 96 + tid];
            }
            float ai = fast_sigmoid(gi), af = fast_sigmoid(gf);
            float ag = fast_tanh(gg),    ao = fast_sigmoid(go);
            c0v = fmaf(af, c0v, ai * ag);
            float h = ao * fast_tanh(c0v);
            xh0[nxt][100 + tid] = h;        // L0's next h
            xh1[nxt][tid]       = h;        // L1's next x
        }
        if (tid >= 64 && tid < 128 && m >= 1) {   // L1 finish
            const int j = tid - 64;
            float gi = bi1, gf = bf1, gg = bg1, go = bo1;
            #pragma unroll
            for (int s = 0; s < 2; ++s) {
                gi += plds[512 + s * 256 + j];
                gf += plds[512 + s * 256 + 64 + j];
                gg += plds[512 + s * 256 + 128 + j];
                go += plds[512 + s * 256 + 192 + j];
            }
            float ai = fast_sigmoid(gi), af = fast_sigmoid(gf);
            float ag = fast_tanh(gg),    ao = fast_sigmoid(go);
            c1v = fmaf(af, c1v, ai * ag);
            float h = ao * fast_tanh(c1v);
            xh1[nxt][32 + j] = h;
            r1[(size_t)b * TT * 64 + (size_t)(m - 1) * 64 + j] = h;
        }
        if (stager && m + 1 < TT) xh0[nxt][tid - 128] = xn;
        __syncthreads();   // bar2: next-step buffers staged
    }
}

// ============================================================================
// Kernel C: LSTM layer 2 (H=128, in=64, K=192) + final projection head fused.
// All 1024 threads GEMV (rows=512, NS=2, P=96 -> 24 float4 = ~96 weight VGPRs;
// needs the pinned waves_per_eu(4,4) budget). Head lags one step: wave 15
// shfl-reduces dot(h2_{t-1}, Wl) during phase A.
// ============================================================================
__global__ __attribute__((amdgpu_flat_work_group_size(1024, 1024)))
           __attribute__((amdgpu_waves_per_eu(4, 4)))
void lstm2_head(const float* __restrict__ r1,    // [B, T, 64]
                const float* __restrict__ Wih2,  // [512, 64]
                const float* __restrict__ Whh2,  // [512, 128]
                const float* __restrict__ b2,    // [512]
                const float* __restrict__ Wl,    // [128]
                const float* __restrict__ bl,    // [1]
                float* __restrict__ r2,          // [B, T, 128]  (output 1)
                float* __restrict__ outp)        // [B, T]       (output 0)
{
    const int b   = blockIdx.x;
    const int tid = threadIdx.x;
    const int s2  = tid >> 9;        // 0..1
    const int j2  = tid & 511;       // gate row

    // --- weight slice: 24 float4 = 96 VGPRs ---
    float4 w[24];
    #pragma unroll
    for (int k4 = 0; k4 < 24; ++k4) {
        float tv[4];
        #pragma unroll
        for (int u = 0; u < 4; ++u) {
            const int e = s2 * 96 + k4 * 4 + u;
            tv[u] = (e < 64) ? Wih2[(size_t)j2 * 64 + e]
                             : Whh2[(size_t)j2 * 128 + (e - 64)];
        }
        w[k4] = make_float4(tv[0], tv[1], tv[2], tv[3]);
    }

    __shared__ alignas(16) float xh2[2][192];   // [r1_t(64) | h2(128)]
    __shared__ float plds[1024];

    const float* rb = r1 + (size_t)b * TT * 64;

    // --- init ---
    float c2v = 0.f;
    float bi2 = 0.f, bf2 = 0.f, bg2 = 0.f, bo2 = 0.f;
    if (tid < 64)  xh2[0][tid] = rb[tid];
    if (tid >= 64 && tid < 192) xh2[0][tid] = 0.f;    // h2_{-1} = 0
    if (tid < 128) {
        bi2 = b2[tid]; bf2 = b2[128 + tid]; bg2 = b2[256 + tid]; bo2 = b2[384 + tid];
    }
    float wl0 = 0.f, wl1 = 0.f, blv = 0.f;
    if (tid >= 960) {
        const int lane = tid - 960;
        wl0 = Wl[2 * lane]; wl1 = Wl[2 * lane + 1]; blv = bl[0];
    }
    const bool stager = (tid >= 128 && tid < 192);
    __syncthreads();

    for (int m = 0; m <= TT; ++m) {
        const int cur = m & 1, nxt = cur ^ 1;

        // ---- phase A: prefetch r1_{m+1}, GEMV(t=m), head(t=m-1) ----
        float rn = 0.f;
        if (stager && m + 1 < TT) rn = rb[(size_t)(m + 1) * 64 + (tid - 128)];

        if (m < TT) {
            const float4* v4 = reinterpret_cast<const float4*>(&xh2[cur][s2 * 96]);
            float4 a = make_float4(0.f, 0.f, 0.f, 0.f);
            #pragma unroll
            for (int k = 0; k < 24; ++k) {
                float4 v = v4[k];
                a.x = fmaf(v.x, w[k].x, a.x); a.y = fmaf(v.y, w[k].y, a.y);
                a.z = fmaf(v.z, w[k].z, a.z); a.w = fmaf(v.w, w[k].w, a.w);
            }
            plds[tid] = (a.x + a.y) + (a.z + a.w);
        }
        if (tid >= 960 && m >= 1) {          // head: whole wave 15, uniform branch
            const int lane = tid - 960;
            float2 hv = *reinterpret_cast<const float2*>(&xh2[cur][64 + 2 * lane]);
            float p = fmaf(hv.x, wl0, hv.y * wl1);
            p += __shfl_xor(p, 1);  p += __shfl_xor(p, 2);  p += __shfl_xor(p, 4);
            p += __shfl_xor(p, 8);  p += __shfl_xor(p, 16); p += __shfl_xor(p, 32);
            if (tid == 960) outp[(size_t)b * TT + (m - 1)] = tanhf(p + blv);
        }
        __syncthreads();   // bar1

        // ---- phase B: L2 state update + staging ----
        if (tid < 128 && m < TT) {
            float gi = bi2, gf = bf2, gg = bg2, go = bo2;
            #pragma unroll
            for (int s = 0; s < 2; ++s) {
                gi += plds[s * 512 + tid];
                gf += plds[s * 512 + 128 + tid];
                gg += plds[s * 512 + 256 + tid];
                go += plds[s * 512 + 384 + tid];
            }
            float ai = fast_sigmoid(gi), af = fast_sigmoid(gf);
            float ag = fast_tanh(gg),    ao = fast_sigmoid(go);
            c2v = fmaf(af, c2v, ai * ag);
            float h = ao * fast_tanh(c2v);
            xh2[nxt][64 + tid] = h;
            r2[(size_t)b * TT * 128 + (size_t)m * 128 + tid] = h;
        }
        if (stager && m + 1 < TT) xh2[nxt][tid - 128] = rn;
        __syncthreads();   // bar2
    }
}

extern "C" void kernel_launch(void* const* d_in, const int* in_sizes, int n_in,
                              void* d_out, int out_size, void* d_ws, size_t ws_size,
                              hipStream_t stream) {
    const float* input = (const float*)d_in[0];
    const float* h_0   = (const float*)d_in[1];
    const float* c_0   = (const float*)d_in[2];
    const float* Wih0  = (const float*)d_in[3];
    const float* Whh0  = (const float*)d_in[4];
    const float* b0    = (const float*)d_in[5];
    const float* Wih1  = (const float*)d_in[6];
    const float* Whh1  = (const float*)d_in[7];
    const float* b1    = (const float*)d_in[8];
    const float* Wih2  = (const float*)d_in[9];
    const float* Whh2  = (const float*)d_in[10];
    const float* b2    = (const float*)d_in[11];
    const float* Wl    = (const float*)d_in[12];
    const float* bl    = (const float*)d_in[13];

    float* out = (float*)d_out;                 // [B*T] head output
    float* r2  = out + (size_t)BB * TT;         // [B,T,128] second output
    float* r1  = (float*)d_ws;                  // [B,T,64] scratch (67 MB)

    hipLaunchKernelGGL(lstm01_fused, dim3(BB), dim3(1024), 0, stream,
                       input, Wih0, Whh0, b0, Wih1, Whh1, b1, h_0, c_0, r1);
    hipLaunchKernelGGL(lstm2_head, dim3(BB), dim3(1024), 0, stream,
                       r1, Wih2, Whh2, b2, Wl, bl, r2, out);
}

// Round 5
// 2364.195 us; speedup vs baseline: 6.4020x; 1.0903x over previous
//
#include <hip/hip_runtime.h>
#include <cmath>

#define TT 1024
#define BB 256

typedef _Float16 half2v __attribute__((ext_vector_type(2)));

__device__ __forceinline__ float fast_rcp(float x) { return __builtin_amdgcn_rcpf(x); }
__device__ __forceinline__ float fast_sigmoid(float x) { return fast_rcp(1.0f + __expf(-x)); }
__device__ __forceinline__ float fast_tanh(float x) {
    return 1.0f - 2.0f * fast_rcp(1.0f + __expf(2.0f * x));
}
__device__ __forceinline__ unsigned pack_f16(float a, float b) {
    half2v h; h.x = (_Float16)a; h.y = (_Float16)b;
    return __builtin_bit_cast(unsigned, h);
}
__device__ __forceinline__ float2 unpack_f16(unsigned u) {
    half2v h = __builtin_bit_cast(half2v, u);
    return make_float2((float)h.x, (float)h.y);
}

// ============================================================================
// Kernel A: fused LSTM layers 0+1 (L1 lagged one step). 1024 threads/block,
// one block per batch element. Weights packed fp16 in registers (<=24 dwords
// per thread, under the observed 64-VGPR budget) and pinned via asm so the
// scheduler cannot sink the loads back into the loop. h/x stay fp32 in LDS.
// ============================================================================
__global__ __attribute__((amdgpu_flat_work_group_size(1024, 1024)))
void lstm01_fused(const float* __restrict__ x,      // [B, T, 100]
                  const float* __restrict__ Wih0,   // [128, 100]
                  const float* __restrict__ Whh0,   // [128, 32]
                  const float* __restrict__ b0,     // [128]
                  const float* __restrict__ Wih1,   // [256, 32]
                  const float* __restrict__ Whh1,   // [256, 64]
                  const float* __restrict__ b1,     // [256]
                  const float* __restrict__ h_0,    // [1, B, 32]
                  const float* __restrict__ c_0,    // [1, B, 32]
                  float* __restrict__ r1)           // [B, T, 64]
{
    const int b   = blockIdx.x;
    const int tid = threadIdx.x;
    const bool isL0 = (tid < 512);
    const int s0 = (tid >> 7) & 3, j0 = tid & 127;   // L0: NS=4, P=36
    const int s1 = (tid >> 8) & 1, j1 = tid & 255;   // L1: NS=2, P=48

    // --- fp16-packed weight slice (shared 24-dword array, role-overlaid) ---
    unsigned wd[24];
    if (isL0) {
        #pragma unroll
        for (int k = 0; k < 18; ++k) {
            float tv[2];
            #pragma unroll
            for (int u = 0; u < 2; ++u) {
                const int e = s0 * 36 + 2 * k + u;
                tv[u] = (e < 100) ? Wih0[(size_t)j0 * 100 + e]
                      : (e < 132) ? Whh0[(size_t)j0 * 32 + (e - 100)] : 0.0f;
            }
            wd[k] = pack_f16(tv[0], tv[1]);
        }
        #pragma unroll
        for (int k = 18; k < 24; ++k) wd[k] = 0u;
    } else {
        #pragma unroll
        for (int k = 0; k < 24; ++k) {
            float tv[2];
            #pragma unroll
            for (int u = 0; u < 2; ++u) {
                const int e = s1 * 48 + 2 * k + u;
                tv[u] = (e < 32) ? Wih1[(size_t)j1 * 32 + e]
                                 : Whh1[(size_t)j1 * 64 + (e - 32)];
            }
            wd[k] = pack_f16(tv[0], tv[1]);
        }
    }
    #pragma unroll
    for (int k = 0; k < 24; ++k) asm volatile("" : "+v"(wd[k]));  // pin

    __shared__ alignas(16) float xh0[2][144];   // [x(100) | h0(32) | pad(12)=0]
    __shared__ alignas(16) float xh1[2][96];    // [h0(32) | h1(64)]
    __shared__ float plds[1024];

    const float* xb = x + (size_t)b * TT * 100;

    float c0v = 0.f, c1v = 0.f;
    float bi0 = 0.f, bf0 = 0.f, bg0 = 0.f, bo0 = 0.f;
    float bi1 = 0.f, bf1 = 0.f, bg1 = 0.f, bo1 = 0.f;
    if (tid < 100) xh0[0][tid] = xb[tid];
    if (tid < 32) {
        xh0[0][100 + tid] = h_0[b * 32 + tid];
        c0v = c_0[b * 32 + tid];
        bi0 = b0[tid]; bf0 = b0[32 + tid]; bg0 = b0[64 + tid]; bo0 = b0[96 + tid];
    }
    if (tid >= 132 && tid < 144) { xh0[0][tid] = 0.f; xh0[1][tid] = 0.f; }
    if (tid < 96) { xh1[0][tid] = 0.f; xh1[1][tid] = 0.f; }
    if (tid >= 64 && tid < 128) {
        const int j = tid - 64;
        bi1 = b1[j]; bf1 = b1[64 + j]; bg1 = b1[128 + j]; bo1 = b1[192 + j];
    }
    const bool stager = (tid >= 128 && tid < 228);
    __syncthreads();

    for (int m = 0; m <= TT; ++m) {
        const int cur = m & 1, nxt = cur ^ 1;

        float xn = 0.f;
        if (stager && m + 1 < TT) xn = xb[(size_t)(m + 1) * 100 + (tid - 128)];

        const bool doG = isL0 ? (m < TT) : (m >= 1);
        if (doG) {
            float4 a = make_float4(0.f, 0.f, 0.f, 0.f);
            if (isL0) {
                const float4* v4 = reinterpret_cast<const float4*>(&xh0[cur][s0 * 36]);
                #pragma unroll
                for (int k = 0; k < 9; ++k) {
                    float4 v = v4[k];
                    float2 wa = unpack_f16(wd[2 * k]);
                    float2 wb = unpack_f16(wd[2 * k + 1]);
                    a.x = fmaf(v.x, wa.x, a.x); a.y = fmaf(v.y, wa.y, a.y);
                    a.z = fmaf(v.z, wb.x, a.z); a.w = fmaf(v.w, wb.y, a.w);
                }
            } else {
                const float4* v4 = reinterpret_cast<const float4*>(&xh1[cur][s1 * 48]);
                #pragma unroll
                for (int k = 0; k < 12; ++k) {
                    float4 v = v4[k];
                    float2 wa = unpack_f16(wd[2 * k]);
                    float2 wb = unpack_f16(wd[2 * k + 1]);
                    a.x = fmaf(v.x, wa.x, a.x); a.y = fmaf(v.y, wa.y, a.y);
                    a.z = fmaf(v.z, wb.x, a.z); a.w = fmaf(v.w, wb.y, a.w);
                }
            }
            plds[tid] = (a.x + a.y) + (a.z + a.w);
        }
        __syncthreads();   // bar1: partials ready

        if (tid < 32 && m < TT) {                 // L0 finish
            float gi = bi0, gf = bf0, gg = bg0, go = bo0;
            #pragma unroll
            for (int s = 0; s < 4; ++s) {
                gi += plds[s * 128 + tid];
                gf += plds[s * 128 + 32 + tid];
                gg += plds[s * 128 + 64 + tid];
                go += plds[s * 128 + 96 + tid];
            }
            float ai = fast_sigmoid(gi), af = fast_sigmoid(gf);
            float ag = fast_tanh(gg),    ao = fast_sigmoid(go);
            c0v = fmaf(af, c0v, ai * ag);
            float h = ao * fast_tanh(c0v);
            xh0[nxt][100 + tid] = h;
            xh1[nxt][tid]       = h;
        }
        if (tid >= 64 && tid < 128 && m >= 1) {   // L1 finish
            const int j = tid - 64;
            float gi = bi1, gf = bf1, gg = bg1, go = bo1;
            #pragma unroll
            for (int s = 0; s < 2; ++s) {
                gi += plds[512 + s * 256 + j];
                gf += plds[512 + s * 256 + 64 + j];
                gg += plds[512 + s * 256 + 128 + j];
                go += plds[512 + s * 256 + 192 + j];
            }
            float ai = fast_sigmoid(gi), af = fast_sigmoid(gf);
            float ag = fast_tanh(gg),    ao = fast_sigmoid(go);
            c1v = fmaf(af, c1v, ai * ag);
            float h = ao * fast_tanh(c1v);
            xh1[nxt][32 + j] = h;
            r1[(size_t)b * TT * 64 + (size_t)(m - 1) * 64 + j] = h;
        }
        if (stager && m + 1 < TT) xh0[nxt][tid - 128] = xn;
        __syncthreads();   // bar2
    }
}

// ============================================================================
// Kernel C: LSTM layer 2 (H=128, K=192) + head. 512 threads/block, NS=1:
// thread j owns full gate row j -> 96 packed-fp16 dwords in registers
// (+overhead ~= 120, under the 128-VGPR budget for 512-thr blocks), pinned.
// No partial reduction; bias folded into the dot. Head lags one step.
// ============================================================================
__global__ __attribute__((amdgpu_flat_work_group_size(512, 512)))
void lstm2_head(const float* __restrict__ r1,    // [B, T, 64]
                const float* __restrict__ Wih2,  // [512, 64]
                const float* __restrict__ Whh2,  // [512, 128]
                const float* __restrict__ b2,    // [512]
                const float* __restrict__ Wl,    // [128]
                const float* __restrict__ bl,    // [1]
                float* __restrict__ r2,          // [B, T, 128]  (output 1)
                float* __restrict__ outp)        // [B, T]       (output 0)
{
    const int b   = blockIdx.x;
    const int tid = threadIdx.x;     // = gate row j

    unsigned wd[96];
    #pragma unroll
    for (int k = 0; k < 96; ++k) {
        float tv[2];
        #pragma unroll
        for (int u = 0; u < 2; ++u) {
            const int e = 2 * k + u;
            tv[u] = (e < 64) ? Wih2[(size_t)tid * 64 + e]
                             : Whh2[(size_t)tid * 128 + (e - 64)];
        }
        wd[k] = pack_f16(tv[0], tv[1]);
    }
    #pragma unroll
    for (int k = 0; k < 96; ++k) asm volatile("" : "+v"(wd[k]));  // pin

    const float bj = b2[tid];

    __shared__ alignas(16) float xh2[2][192];   // [r1_t(64) | h2(128)]
    __shared__ float g_lds[512];

    const float* rb = r1 + (size_t)b * TT * 64;

    float c2v = 0.f;
    if (tid < 64)  xh2[0][tid] = rb[tid];
    if (tid >= 64 && tid < 192) xh2[0][tid] = 0.f;   // h2_{-1} = 0
    float wl0 = 0.f, wl1 = 0.f, blv = 0.f;
    if (tid >= 448) {
        const int lane = tid - 448;
        wl0 = Wl[2 * lane]; wl1 = Wl[2 * lane + 1]; blv = bl[0];
    }
    const bool stager = (tid >= 128 && tid < 192);
    __syncthreads();

    for (int m = 0; m <= TT; ++m) {
        const int cur = m & 1, nxt = cur ^ 1;

        float rn = 0.f;
        if (stager && m + 1 < TT) rn = rb[(size_t)(m + 1) * 64 + (tid - 128)];

        if (m < TT) {
            const float4* v4 = reinterpret_cast<const float4*>(&xh2[cur][0]);
            float4 a = make_float4(bj, 0.f, 0.f, 0.f);
            #pragma unroll
            for (int k = 0; k < 48; ++k) {
                float4 v = v4[k];
                float2 wa = unpack_f16(wd[2 * k]);
                float2 wb = unpack_f16(wd[2 * k + 1]);
                a.x = fmaf(v.x, wa.x, a.x); a.y = fmaf(v.y, wa.y, a.y);
                a.z = fmaf(v.z, wb.x, a.z); a.w = fmaf(v.w, wb.y, a.w);
            }
            g_lds[tid] = (a.x + a.y) + (a.z + a.w);
        }
        if (tid >= 448 && m >= 1) {              // head for t = m-1 (wave 7)
            const int lane = tid - 448;
            float2 hv = *reinterpret_cast<const float2*>(&xh2[cur][64 + 2 * lane]);
            float p = fmaf(hv.x, wl0, hv.y * wl1);
            p += __shfl_xor(p, 1);  p += __shfl_xor(p, 2);  p += __shfl_xor(p, 4);
            p += __shfl_xor(p, 8);  p += __shfl_xor(p, 16); p += __shfl_xor(p, 32);
            if (tid == 448) outp[(size_t)b * TT + (m - 1)] = tanhf(p + blv);
        }
        __syncthreads();   // bar1: g + head input consumed

        if (tid < 128 && m < TT) {
            float gi = g_lds[tid];
            float gf = g_lds[128 + tid];
            float gg = g_lds[256 + tid];
            float go = g_lds[384 + tid];
            float ai = fast_sigmoid(gi), af = fast_sigmoid(gf);
            float ag = fast_tanh(gg),    ao = fast_sigmoid(go);
            c2v = fmaf(af, c2v, ai * ag);
            float h = ao * fast_tanh(c2v);
            xh2[nxt][64 + tid] = h;
            r2[(size_t)b * TT * 128 + (size_t)m * 128 + tid] = h;
        }
        if (stager && m + 1 < TT) xh2[nxt][tid - 128] = rn;
        __syncthreads();   // bar2
    }
}

extern "C" void kernel_launch(void* const* d_in, const int* in_sizes, int n_in,
                              void* d_out, int out_size, void* d_ws, size_t ws_size,
                              hipStream_t stream) {
    const float* input = (const float*)d_in[0];
    const float* h_0   = (const float*)d_in[1];
    const float* c_0   = (const float*)d_in[2];
    const float* Wih0  = (const float*)d_in[3];
    const float* Whh0  = (const float*)d_in[4];
    const float* b0    = (const float*)d_in[5];
    const float* Wih1  = (const float*)d_in[6];
    const float* Whh1  = (const float*)d_in[7];
    const float* b1    = (const float*)d_in[8];
    const float* Wih2  = (const float*)d_in[9];
    const float* Whh2  = (const float*)d_in[10];
    const float* b2    = (const float*)d_in[11];
    const float* Wl    = (const float*)d_in[12];
    const float* bl    = (const float*)d_in[13];

    float* out = (float*)d_out;                 // [B*T] head output
    float* r2  = out + (size_t)BB * TT;         // [B,T,128] second output
    float* r1  = (float*)d_ws;                  // [B,T,64] scratch (67 MB)

    hipLaunchKernelGGL(lstm01_fused, dim3(BB), dim3(1024), 0, stream,
                       input, Wih0, Whh0, b0, Wih1, Whh1, b1, h_0, c_0, r1);
    hipLaunchKernelGGL(lstm2_head, dim3(BB), dim3(512), 0, stream,
                       r1, Wih2, Whh2, b2, Wl, bl, r2, out);
}

// Round 6
// 1865.366 us; speedup vs baseline: 8.1140x; 1.2674x over previous
//
#include <hip/hip_runtime.h>
#include <cmath>

#define TT 1024
#define BB 256

typedef _Float16 half2v __attribute__((ext_vector_type(2)));

__device__ __forceinline__ float fast_rcp(float x) { return __builtin_amdgcn_rcpf(x); }
__device__ __forceinline__ float fast_sigmoid(float x) { return fast_rcp(1.0f + __expf(-x)); }
__device__ __forceinline__ float fast_tanh(float x) {
    return 1.0f - 2.0f * fast_rcp(1.0f + __expf(2.0f * x));
}
__device__ __forceinline__ unsigned pack_f16(float a, float b) {
    half2v h; h.x = (_Float16)a; h.y = (_Float16)b;
    return __builtin_bit_cast(unsigned, h);
}
__device__ __forceinline__ half2v as_h2(unsigned u) {
    return __builtin_bit_cast(half2v, u);
}
// D = a.x*b.x + a.y*b.y + c, f32 accumulate (V_DOT2_F32_F16)
__device__ __forceinline__ float fdot2(unsigned a, unsigned b, float c) {
#if __has_builtin(__builtin_amdgcn_fdot2)
    return __builtin_amdgcn_fdot2(as_h2(a), as_h2(b), c, false);
#else
    float d;
    asm("v_dot2_f32_f16 %0, %1, %2, %3" : "=v"(d) : "v"(a), "v"(b), "v"(c));
    return d;
#endif
}

// ============================================================================
// Kernel A: fused LSTM layers 0+1 (L1 lagged one step). 1024 thr/block, one
// block per batch element. Weights fp16-packed in registers (<=24 dwords,
// pinned); x/h stored as packed f16 in LDS; GEMV via v_dot2_f32_f16.
//   L0: tid[0,512)  NS=4, rows 128, slice 36 halves (9 x ds_read_b64, 18 dot2)
//   L1: tid[512,1024) NS=2, rows 256, slice 48 halves (6 x ds_read_b128, 24 dot2)
// ============================================================================
__global__ __attribute__((amdgpu_flat_work_group_size(1024, 1024)))
void lstm01_fused(const float* __restrict__ x,      // [B, T, 100]
                  const float* __restrict__ Wih0,   // [128, 100]
                  const float* __restrict__ Whh0,   // [128, 32]
                  const float* __restrict__ b0,     // [128]
                  const float* __restrict__ Wih1,   // [256, 32]
                  const float* __restrict__ Whh1,   // [256, 64]
                  const float* __restrict__ b1,     // [256]
                  const float* __restrict__ h_0,    // [1, B, 32]
                  const float* __restrict__ c_0,    // [1, B, 32]
                  _Float16* __restrict__ r1)        // [B, T, 64] fp16
{
    const int b   = blockIdx.x;
    const int tid = threadIdx.x;
    const bool isL0 = (tid < 512);
    const int s0 = (tid >> 7) & 3, j0 = tid & 127;   // L0: NS=4, P=36
    const int s1 = (tid >> 8) & 1, j1 = tid & 255;   // L1: NS=2, P=48

    // --- fp16-packed weight slice (24 dwords, role-overlaid), pinned ---
    unsigned wd[24];
    if (isL0) {
        #pragma unroll
        for (int k = 0; k < 18; ++k) {
            float tv[2];
            #pragma unroll
            for (int u = 0; u < 2; ++u) {
                const int e = s0 * 36 + 2 * k + u;
                tv[u] = (e < 100) ? Wih0[(size_t)j0 * 100 + e]
                      : (e < 132) ? Whh0[(size_t)j0 * 32 + (e - 100)] : 0.0f;
            }
            wd[k] = pack_f16(tv[0], tv[1]);
        }
        #pragma unroll
        for (int k = 18; k < 24; ++k) wd[k] = 0u;
    } else {
        #pragma unroll
        for (int k = 0; k < 24; ++k) {
            float tv[2];
            #pragma unroll
            for (int u = 0; u < 2; ++u) {
                const int e = s1 * 48 + 2 * k + u;
                tv[u] = (e < 32) ? Wih1[(size_t)j1 * 32 + e]
                                 : Whh1[(size_t)j1 * 64 + (e - 32)];
            }
            wd[k] = pack_f16(tv[0], tv[1]);
        }
    }
    #pragma unroll
    for (int k = 0; k < 24; ++k) asm volatile("" : "+v"(wd[k]));  // pin

    __shared__ alignas(16) _Float16 xh0[2][144];  // [x(100)|h0(32)|pad(12)=0]
    __shared__ alignas(16) _Float16 xh1[2][96];   // [h0(32)|h1(64)]
    __shared__ float plds[1024];

    const float* xb = x + (size_t)b * TT * 100;

    float c0v = 0.f, c1v = 0.f;
    float bi0 = 0.f, bf0 = 0.f, bg0 = 0.f, bo0 = 0.f;
    float bi1 = 0.f, bf1 = 0.f, bg1 = 0.f, bo1 = 0.f;
    if (tid < 100) xh0[0][tid] = (_Float16)xb[tid];
    if (tid < 32) {
        xh0[0][100 + tid] = (_Float16)h_0[b * 32 + tid];
        c0v = c_0[b * 32 + tid];
        bi0 = b0[tid]; bf0 = b0[32 + tid]; bg0 = b0[64 + tid]; bo0 = b0[96 + tid];
    }
    if (tid >= 132 && tid < 144) { xh0[0][tid] = (_Float16)0.f; xh0[1][tid] = (_Float16)0.f; }
    if (tid < 96) { xh1[0][tid] = (_Float16)0.f; xh1[1][tid] = (_Float16)0.f; }
    if (tid >= 64 && tid < 128) {
        const int j = tid - 64;
        bi1 = b1[j]; bf1 = b1[64 + j]; bg1 = b1[128 + j]; bo1 = b1[192 + j];
    }
    const bool stager = (tid >= 128 && tid < 228);
    __syncthreads();

    for (int m = 0; m <= TT; ++m) {
        const int cur = m & 1, nxt = cur ^ 1;

        float xn = 0.f;
        if (stager && m + 1 < TT) xn = xb[(size_t)(m + 1) * 100 + (tid - 128)];

        const bool doG = isL0 ? (m < TT) : (m >= 1);
        if (doG) {
            float a0 = 0.f, a1 = 0.f;
            if (isL0) {
                const uint2* v2 = reinterpret_cast<const uint2*>(&xh0[cur][s0 * 36]);
                #pragma unroll
                for (int k = 0; k < 9; ++k) {
                    uint2 v = v2[k];
                    a0 = fdot2(v.x, wd[2 * k], a0);
                    a1 = fdot2(v.y, wd[2 * k + 1], a1);
                }
            } else {
                const uint4* v4 = reinterpret_cast<const uint4*>(&xh1[cur][s1 * 48]);
                #pragma unroll
                for (int k = 0; k < 6; ++k) {
                    uint4 v = v4[k];
                    a0 = fdot2(v.x, wd[4 * k],     a0);
                    a1 = fdot2(v.y, wd[4 * k + 1], a1);
                    a0 = fdot2(v.z, wd[4 * k + 2], a0);
                    a1 = fdot2(v.w, wd[4 * k + 3], a1);
                }
            }
            plds[tid] = a0 + a1;
        }
        __syncthreads();   // bar1: partials ready

        if (tid < 32 && m < TT) {                 // L0 finish
            float gi = bi0, gf = bf0, gg = bg0, go = bo0;
            #pragma unroll
            for (int s = 0; s < 4; ++s) {
                gi += plds[s * 128 + tid];
                gf += plds[s * 128 + 32 + tid];
                gg += plds[s * 128 + 64 + tid];
                go += plds[s * 128 + 96 + tid];
            }
            float ai = fast_sigmoid(gi), af = fast_sigmoid(gf);
            float ag = fast_tanh(gg),    ao = fast_sigmoid(go);
            c0v = fmaf(af, c0v, ai * ag);
            float h = ao * fast_tanh(c0v);
            _Float16 hh = (_Float16)h;
            xh0[nxt][100 + tid] = hh;
            xh1[nxt][tid]       = hh;
        }
        if (tid >= 64 && tid < 128 && m >= 1) {   // L1 finish (t = m-1)
            const int j = tid - 64;
            float gi = bi1, gf = bf1, gg = bg1, go = bo1;
            #pragma unroll
            for (int s = 0; s < 2; ++s) {
                gi += plds[512 + s * 256 + j];
                gf += plds[512 + s * 256 + 64 + j];
                gg += plds[512 + s * 256 + 128 + j];
                go += plds[512 + s * 256 + 192 + j];
            }
            float ai = fast_sigmoid(gi), af = fast_sigmoid(gf);
            float ag = fast_tanh(gg),    ao = fast_sigmoid(go);
            c1v = fmaf(af, c1v, ai * ag);
            float h = ao * fast_tanh(c1v);
            _Float16 hh = (_Float16)h;
            xh1[nxt][32 + j] = hh;
            r1[(size_t)b * TT * 64 + (size_t)(m - 1) * 64 + j] = hh;
        }
        if (stager && m + 1 < TT) xh0[nxt][tid - 128] = (_Float16)xn;
        __syncthreads();   // bar2
    }
}

// ============================================================================
// Kernel C: LSTM layer 2 (H=128, K=192) + head. 1024 thr/block, NS=2:
// thread (s2,j2) holds 48 packed-fp16 dwords (pinned, under the 64-VGPR
// budget); GEMV = 12 ds_read_b128 + 48 v_dot2_f32_f16. 4 waves/SIMD TLP.
// Head (wave 15) runs in phase B on the idle waves.
// ============================================================================
__global__ __attribute__((amdgpu_flat_work_group_size(1024, 1024)))
void lstm2_head(const _Float16* __restrict__ r1,  // [B, T, 64] fp16
                const float* __restrict__ Wih2,   // [512, 64]
                const float* __restrict__ Whh2,   // [512, 128]
                const float* __restrict__ b2,     // [512]
                const float* __restrict__ Wl,     // [128]
                const float* __restrict__ bl,     // [1]
                float* __restrict__ r2,           // [B, T, 128]  (output 1)
                float* __restrict__ outp)         // [B, T]       (output 0)
{
    const int b   = blockIdx.x;
    const int tid = threadIdx.x;
    const int s2  = tid >> 9;        // 0..1
    const int j2  = tid & 511;       // gate row

    unsigned wd[48];
    #pragma unroll
    for (int k = 0; k < 48; ++k) {
        float tv[2];
        #pragma unroll
        for (int u = 0; u < 2; ++u) {
            const int e = s2 * 96 + 2 * k + u;
            tv[u] = (e < 64) ? Wih2[(size_t)j2 * 64 + e]
                             : Whh2[(size_t)j2 * 128 + (e - 64)];
        }
        wd[k] = pack_f16(tv[0], tv[1]);
    }
    #pragma unroll
    for (int k = 0; k < 48; ++k) asm volatile("" : "+v"(wd[k]));  // pin

    __shared__ alignas(16) _Float16 xh2[2][192];  // [r1_t(64)|h2(128)]
    __shared__ float plds[1024];

    const _Float16* rb = r1 + (size_t)b * TT * 64;

    float c2v = 0.f;
    float bi2 = 0.f, bf2 = 0.f, bg2 = 0.f, bo2 = 0.f;
    if (tid < 64)  xh2[0][tid] = rb[tid];
    if (tid >= 64 && tid < 192) xh2[0][tid] = (_Float16)0.f;   // h2_{-1}=0
    if (tid < 128) {
        bi2 = b2[tid]; bf2 = b2[128 + tid]; bg2 = b2[256 + tid]; bo2 = b2[384 + tid];
    }
    unsigned wlp = 0; float blv = 0.f;
    if (tid >= 960) {
        const int lane = tid - 960;
        wlp = pack_f16(Wl[2 * lane], Wl[2 * lane + 1]);
        blv = bl[0];
    }
    const bool stager = (tid >= 128 && tid < 192);
    __syncthreads();

    for (int m = 0; m <= TT; ++m) {
        const int cur = m & 1, nxt = cur ^ 1;

        // ---- phase A: prefetch r1_{m+1} (f16), GEMV(t=m) ----
        _Float16 rn = (_Float16)0.f;
        if (stager && m + 1 < TT) rn = rb[(size_t)(m + 1) * 64 + (tid - 128)];

        if (m < TT) {
            const uint4* v4 = reinterpret_cast<const uint4*>(&xh2[cur][s2 * 96]);
            float a0 = 0.f, a1 = 0.f, a2 = 0.f, a3 = 0.f;
            #pragma unroll
            for (int k = 0; k < 12; ++k) {
                uint4 v = v4[k];
                a0 = fdot2(v.x, wd[4 * k],     a0);
                a1 = fdot2(v.y, wd[4 * k + 1], a1);
                a2 = fdot2(v.z, wd[4 * k + 2], a2);
                a3 = fdot2(v.w, wd[4 * k + 3], a3);
            }
            plds[tid] = (a0 + a1) + (a2 + a3);
        }
        __syncthreads();   // bar1: partials ready

        // ---- phase B: finish + staging + head (disjoint waves) ----
        if (tid < 128 && m < TT) {
            float gi = bi2 + plds[tid]       + plds[512 + tid];
            float gf = bf2 + plds[128 + tid] + plds[640 + tid];
            float gg = bg2 + plds[256 + tid] + plds[768 + tid];
            float go = bo2 + plds[384 + tid] + plds[896 + tid];
            float ai = fast_sigmoid(gi), af = fast_sigmoid(gf);
            float ag = fast_tanh(gg),    ao = fast_sigmoid(go);
            c2v = fmaf(af, c2v, ai * ag);
            float h = ao * fast_tanh(c2v);
            xh2[nxt][64 + tid] = (_Float16)h;
            r2[(size_t)b * TT * 128 + (size_t)m * 128 + tid] = h;
        }
        if (stager && m + 1 < TT) xh2[nxt][tid - 128] = rn;
        if (tid >= 960 && m >= 1) {          // head for t=m-1 (wave 15, idle here)
            const int lane = tid - 960;
            unsigned hv = reinterpret_cast<const unsigned*>(&xh2[cur][0])[32 + lane];
            float p = fdot2(hv, wlp, 0.f);
            p += __shfl_xor(p, 1);  p += __shfl_xor(p, 2);  p += __shfl_xor(p, 4);
            p += __shfl_xor(p, 8);  p += __shfl_xor(p, 16); p += __shfl_xor(p, 32);
            if (tid == 960) outp[(size_t)b * TT + (m - 1)] = tanhf(p + blv);
        }
        __syncthreads();   // bar2
    }
}

extern "C" void kernel_launch(void* const* d_in, const int* in_sizes, int n_in,
                              void* d_out, int out_size, void* d_ws, size_t ws_size,
                              hipStream_t stream) {
    const float* input = (const float*)d_in[0];
    const float* h_0   = (const float*)d_in[1];
    const float* c_0   = (const float*)d_in[2];
    const float* Wih0  = (const float*)d_in[3];
    const float* Whh0  = (const float*)d_in[4];
    const float* b0    = (const float*)d_in[5];
    const float* Wih1  = (const float*)d_in[6];
    const float* Whh1  = (const float*)d_in[7];
    const float* b1    = (const float*)d_in[8];
    const float* Wih2  = (const float*)d_in[9];
    const float* Whh2  = (const float*)d_in[10];
    const float* b2    = (const float*)d_in[11];
    const float* Wl    = (const float*)d_in[12];
    const float* bl    = (const float*)d_in[13];

    float* out = (float*)d_out;                 // [B*T] head output
    float* r2  = out + (size_t)BB * TT;         // [B,T,128] second output
    _Float16* r1 = (_Float16*)d_ws;             // [B,T,64] fp16 scratch (33.5 MB)

    hipLaunchKernelGGL(lstm01_fused, dim3(BB), dim3(1024), 0, stream,
                       input, Wih0, Whh0, b0, Wih1, Whh1, b1, h_0, c_0, r1);
    hipLaunchKernelGGL(lstm2_head, dim3(BB), dim3(1024), 0, stream,
                       r1, Wih2, Whh2, b2, Wl, bl, r2, out);
}

// Round 7
// 1748.966 us; speedup vs baseline: 8.6540x; 1.0666x over previous
//
#include <hip/hip_runtime.h>
#include <cmath>

#define TT 1024
#define BB 256
#define GG 16            // batch elements per block
#define NBLK (BB / GG)   // 16 blocks

typedef _Float16 f16x8 __attribute__((ext_vector_type(8)));
typedef float    f32x4 __attribute__((ext_vector_type(4)));
typedef _Float16 half2v __attribute__((ext_vector_type(2)));

__device__ __forceinline__ float fast_rcp(float x) { return __builtin_amdgcn_rcpf(x); }
__device__ __forceinline__ float fast_sigmoid(float x) { return fast_rcp(1.0f + __expf(-x)); }
__device__ __forceinline__ float fast_tanh(float x) {
    return 1.0f - 2.0f * fast_rcp(1.0f + __expf(2.0f * x));
}
__device__ __forceinline__ unsigned pack_f16(float a, float b) {
    half2v h; h.x = (_Float16)a; h.y = (_Float16)b;
    return __builtin_bit_cast(unsigned, h);
}
__device__ __forceinline__ float2 unpack_f16(unsigned u) {
    half2v h = __builtin_bit_cast(half2v, u);
    return make_float2((float)h.x, (float)h.y);
}
__device__ __forceinline__ void pin4(uint4& u) {
    asm volatile("" : "+v"(u.x), "+v"(u.y), "+v"(u.z), "+v"(u.w));
}

// ============================================================================
// One-time weight reorder into MFMA A-fragment order (fp16).
// A-frag convention (consistent for A and B): lane l holds row (l&15) of the
// 16-row tile, k = kt*32 + (l>>4)*8 + j, j=0..7.  Row permutation is
// gate-interleaved: tile (w,g) = gate g, hidden [16w,16w+16).
//   wfC : [8][4][6][64][8]  (L2: rows 512, K=192)
//   wfA0: [2][4][5][64][8]  (L0: rows 128, K=132 padded to 160, zeros beyond)
//   wfA1: [4][4][3][64][8]  (L1: rows 256, K=96)
// ============================================================================
__global__ __launch_bounds__(256) void reorder_wf(
    const float* __restrict__ Wih0, const float* __restrict__ Whh0,
    const float* __restrict__ Wih1, const float* __restrict__ Whh1,
    const float* __restrict__ Wih2, const float* __restrict__ Whh2,
    _Float16* __restrict__ wfA0, _Float16* __restrict__ wfA1,
    _Float16* __restrict__ wfC)
{
    int idx = blockIdx.x * 256 + threadIdx.x;
    if (idx < 98304) {                       // C section
        int j = idx & 7, l = (idx >> 3) & 63, t = idx >> 9;  // t=(w*4+g)*6+kt
        int kt = t % 6, g = (t / 6) & 3, w = t / 24;
        int row = g * 128 + 16 * w + (l & 15);
        int k = kt * 32 + ((l >> 4) << 3) + j;
        float v = (k < 64) ? Wih2[row * 64 + k] : Whh2[row * 128 + (k - 64)];
        wfC[idx] = (_Float16)v;
    } else if (idx < 118784) {               // A0 section
        int f = idx - 98304;
        int j = f & 7, l = (f >> 3) & 63, t = f >> 9;        // t=(w*4+g)*5+kt
        int kt = t % 5, g = (t / 5) & 3, w = t / 20;
        int row = g * 32 + 16 * w + (l & 15);
        int k = kt * 32 + ((l >> 4) << 3) + j;
        float v = (k < 100) ? Wih0[row * 100 + k]
                : (k < 132) ? Whh0[row * 32 + (k - 100)] : 0.0f;
        wfA0[f] = (_Float16)v;
    } else if (idx < 143360) {               // A1 section
        int f = idx - 118784;
        int j = f & 7, l = (f >> 3) & 63, t = f >> 9;        // t=(w*4+g)*3+kt
        int kt = t % 3, g = (t / 3) & 3, w = t / 12;
        int row = g * 64 + 16 * w + (l & 15);
        int k = kt * 32 + ((l >> 4) << 3) + j;
        float v = (k < 32) ? Wih1[row * 32 + k] : Whh1[row * 64 + (k - 32)];
        wfA1[f] = (_Float16)v;
    }
}

// ============================================================================
// Kernel A: fused LSTM layers 0+1 via MFMA, G=16 batch/block, 16 blocks,
// 512 threads (8 waves): waves 0-1 = L0 GEMM, 2-5 = L1 GEMM (lagged 1 step),
// 6-7 = x stagers. Gate-interleaved tiles -> register-local c/h update.
// One barrier per step; X buffers transposed [col][K] f16, double-buffered.
// ============================================================================
__global__ __attribute__((amdgpu_flat_work_group_size(512, 512),
                          amdgpu_waves_per_eu(1, 2)))
void lstm01_mfma(const float* __restrict__ x,       // [B, T, 100]
                 const _Float16* __restrict__ wfA0,
                 const _Float16* __restrict__ wfA1,
                 const float* __restrict__ b0_,     // [128]
                 const float* __restrict__ b1_,     // [256]
                 const float* __restrict__ h_0,     // [1, B, 32]
                 const float* __restrict__ c_0,     // [1, B, 32]
                 unsigned* __restrict__ r1u)        // [B, T, 32] uints (64 f16)
{
    const int b0b = blockIdx.x * GG;
    const int tid = threadIdx.x;
    const int w = tid >> 6, l = tid & 63;
    const int l15 = l & 15, lq = l >> 4;
    const int jb = ((w < 2) ? 16 * w : 16 * (w - 2)) + lq * 4;  // lane hidden base

    __shared__ alignas(16) _Float16 X0T[2][GG][168];  // [x(100)|h0(100..132)|0-pad(132..160)|unused]
    __shared__ alignas(16) _Float16 X1T[2][GG][104];  // [h0(32)|h1(32..96)|pad]

    // --- role setup: A-fragments (pinned), biases, c-state ---
    uint4 afu[4][5];
    unsigned bpk[8];
    float c[4] = {0.f, 0.f, 0.f, 0.f};
    if (w < 2) {                               // L0
        const uint4* wf4 = reinterpret_cast<const uint4*>(wfA0);
        #pragma unroll
        for (int g = 0; g < 4; ++g)
            #pragma unroll
            for (int kt = 0; kt < 5; ++kt) {
                afu[g][kt] = wf4[((w * 4 + g) * 5 + kt) * 64 + l];
                pin4(afu[g][kt]);
            }
        #pragma unroll
        for (int g = 0; g < 4; ++g)
            #pragma unroll
            for (int p = 0; p < 2; ++p)
                bpk[g * 2 + p] = pack_f16(b0_[g * 32 + jb + 2 * p],
                                          b0_[g * 32 + jb + 2 * p + 1]);
        #pragma unroll
        for (int r = 0; r < 4; ++r) c[r] = c_0[(b0b + l15) * 32 + jb + r];
    } else if (w < 6) {                        // L1
        const int w1 = w - 2;
        const uint4* wf4 = reinterpret_cast<const uint4*>(wfA1);
        #pragma unroll
        for (int g = 0; g < 4; ++g)
            #pragma unroll
            for (int kt = 0; kt < 3; ++kt) {
                afu[g][kt] = wf4[((w1 * 4 + g) * 3 + kt) * 64 + l];
                pin4(afu[g][kt]);
            }
        #pragma unroll
        for (int g = 0; g < 4; ++g)
            #pragma unroll
            for (int p = 0; p < 2; ++p)
                bpk[g * 2 + p] = pack_f16(b1_[g * 64 + jb + 2 * p],
                                          b1_[g * 64 + jb + 2 * p + 1]);
    }

    // --- init LDS ---
    {
        const int col = tid >> 5, u = tid & 31;
        // x(0) -> X0T[0]
        #pragma unroll
        for (int kk = 0; kk < 4; ++kk) {
            int i = u + 32 * kk;
            if (i < 100)
                X0T[0][col][i] = (_Float16)x[((size_t)(b0b + col) * TT) * 100 + i];
        }
        if (u < 32) X0T[0][col][100 + u] = (_Float16)h_0[(b0b + col) * 32 + u];
        if (u < 28) { X0T[0][col][132 + u] = (_Float16)0.f;
                      X0T[1][col][132 + u] = (_Float16)0.f; }
        #pragma unroll
        for (int kk = 0; kk < 2; ++kk) {
            int uu = u + 32 * kk;
            if (uu < 52) {
                *reinterpret_cast<unsigned*>(&X1T[0][col][2 * uu]) = 0u;
                *reinterpret_cast<unsigned*>(&X1T[1][col][2 * uu]) = 0u;
            }
        }
    }
    __syncthreads();

    const int sb = (tid - 384) >> 3, si = (tid - 384) & 7;  // stager mapping

    for (int m = 0; m <= TT; ++m) {
        const int cur = m & 1, nxt = cur ^ 1;

        if (w < 2) {                                  // ---- L0: h0(m) ----
            if (m < TT) {
                f32x4 acc[4];
                #pragma unroll
                for (int g = 0; g < 4; ++g) {
                    float2 u0 = unpack_f16(bpk[2 * g]);
                    float2 u1 = unpack_f16(bpk[2 * g + 1]);
                    acc[g] = (f32x4){u0.x, u0.y, u1.x, u1.y};
                }
                #pragma unroll
                for (int kt = 0; kt < 5; ++kt) {
                    f16x8 bf = *reinterpret_cast<const f16x8*>(
                        &X0T[cur][l15][kt * 32 + lq * 8]);
                    #pragma unroll
                    for (int g = 0; g < 4; ++g)
                        acc[g] = __builtin_amdgcn_mfma_f32_16x16x32_f16(
                            __builtin_bit_cast(f16x8, afu[g][kt]), bf, acc[g], 0, 0, 0);
                }
                float h[4];
                #pragma unroll
                for (int r = 0; r < 4; ++r) {
                    float ai = fast_sigmoid(acc[0][r]);
                    float afg = fast_sigmoid(acc[1][r]);
                    float ag = fast_tanh(acc[2][r]);
                    float ao = fast_sigmoid(acc[3][r]);
                    c[r] = fmaf(afg, c[r], ai * ag);
                    h[r] = ao * fast_tanh(c[r]);
                }
                uint2 hp = make_uint2(pack_f16(h[0], h[1]), pack_f16(h[2], h[3]));
                *reinterpret_cast<uint2*>(&X0T[nxt][l15][100 + jb]) = hp;
                *reinterpret_cast<uint2*>(&X1T[nxt][l15][jb]) = hp;
            }
        } else if (w < 6) {                           // ---- L1: h1(m-1) ----
            if (m >= 1) {
                f32x4 acc[4];
                #pragma unroll
                for (int g = 0; g < 4; ++g) {
                    float2 u0 = unpack_f16(bpk[2 * g]);
                    float2 u1 = unpack_f16(bpk[2 * g + 1]);
                    acc[g] = (f32x4){u0.x, u0.y, u1.x, u1.y};
                }
                #pragma unroll
                for (int kt = 0; kt < 3; ++kt) {
                    f16x8 bf = *reinterpret_cast<const f16x8*>(
                        &X1T[cur][l15][kt * 32 + lq * 8]);
                    #pragma unroll
                    for (int g = 0; g < 4; ++g)
                        acc[g] = __builtin_amdgcn_mfma_f32_16x16x32_f16(
                            __builtin_bit_cast(f16x8, afu[g][kt]), bf, acc[g], 0, 0, 0);
                }
                float h[4];
                #pragma unroll
                for (int r = 0; r < 4; ++r) {
                    float ai = fast_sigmoid(acc[0][r]);
                    float afg = fast_sigmoid(acc[1][r]);
                    float ag = fast_tanh(acc[2][r]);
                    float ao = fast_sigmoid(acc[3][r]);
                    c[r] = fmaf(afg, c[r], ai * ag);
                    h[r] = ao * fast_tanh(c[r]);
                }
                uint2 hp = make_uint2(pack_f16(h[0], h[1]), pack_f16(h[2], h[3]));
                *reinterpret_cast<uint2*>(&X1T[nxt][l15][32 + jb]) = hp;
                *reinterpret_cast<uint2*>(
                    r1u + (((size_t)(b0b + l15) * TT + (m - 1)) * 32 + (jb >> 1))) = hp;
            }
        } else {                                      // ---- stagers: x(m+1) ----
            if (m + 1 < TT) {
                const float* xr = x + ((size_t)(b0b + sb) * TT + (m + 1)) * 100;
                float xv[13];
                #pragma unroll
                for (int k = 0; k < 13; ++k) {
                    int i = si + 8 * k;
                    xv[k] = (i < 100) ? xr[i] : 0.f;
                }
                #pragma unroll
                for (int k = 0; k < 13; ++k) {
                    int i = si + 8 * k;
                    if (i < 100) X0T[nxt][sb][i] = (_Float16)xv[k];
                }
            }
        }
        __syncthreads();   // single barrier: cur fully consumed, nxt fully staged
    }
}

// ============================================================================
// Kernel C: LSTM layer 2 via MFMA. 512 threads (8 waves), all GEMM.
// Wave w: gate tiles i,f,g,o for hidden [16w,16w+16), K=192 (6 K-tiles).
// A-frags 96 VGPR pinned; B = ds_read_b128 from XT[col][K]; 1 barrier/step.
// ============================================================================
__global__ __attribute__((amdgpu_flat_work_group_size(512, 512),
                          amdgpu_waves_per_eu(1, 2)))
void lstm2_mfma(const unsigned* __restrict__ r1u,   // [B, T, 32] uints
                const _Float16* __restrict__ wfC,
                const float* __restrict__ b2,       // [512]
                float* __restrict__ r2)             // [B, T, 128]
{
    const int b0b = blockIdx.x * GG;
    const int tid = threadIdx.x;
    const int w = tid >> 6, l = tid & 63;
    const int l15 = l & 15, lq = l >> 4;
    const int jb = 16 * w + lq * 4;

    uint4 af[4][6];
    {
        const uint4* wf4 = reinterpret_cast<const uint4*>(wfC);
        #pragma unroll
        for (int g = 0; g < 4; ++g)
            #pragma unroll
            for (int kt = 0; kt < 6; ++kt) {
                af[g][kt] = wf4[((w * 4 + g) * 6 + kt) * 64 + l];
                pin4(af[g][kt]);
            }
    }
    unsigned bpk[8];
    #pragma unroll
    for (int g = 0; g < 4; ++g)
        #pragma unroll
        for (int p = 0; p < 2; ++p)
            bpk[g * 2 + p] = pack_f16(b2[g * 128 + jb + 2 * p],
                                      b2[g * 128 + jb + 2 * p + 1]);

    __shared__ alignas(16) _Float16 XT[2][GG][200];   // [r1(0..64)|h2(64..192)|pad]

    const int sc = tid >> 5, su = tid & 31;
    {   // init: r1(0) + zero h2 (buffer 0)
        unsigned v = r1u[((size_t)(b0b + sc) * TT) * 32 + su];
        *reinterpret_cast<unsigned*>(&XT[0][sc][2 * su]) = v;
        *reinterpret_cast<uint2*>(&XT[0][sc][64 + su * 4]) = make_uint2(0u, 0u);
    }
    __syncthreads();

    float c[4] = {0.f, 0.f, 0.f, 0.f};

    for (int m = 0; m < TT; ++m) {
        const int cur = m & 1, nxt = cur ^ 1;

        unsigned rn = 0;                              // prefetch r1(m+1)
        if (m + 1 < TT) rn = r1u[((size_t)(b0b + sc) * TT + (m + 1)) * 32 + su];

        f32x4 acc[4];
        #pragma unroll
        for (int g = 0; g < 4; ++g) {
            float2 u0 = unpack_f16(bpk[2 * g]);
            float2 u1 = unpack_f16(bpk[2 * g + 1]);
            acc[g] = (f32x4){u0.x, u0.y, u1.x, u1.y};
        }
        #pragma unroll
        for (int kt = 0; kt < 6; ++kt) {
            f16x8 bf = *reinterpret_cast<const f16x8*>(&XT[cur][l15][kt * 32 + lq * 8]);
            #pragma unroll
            for (int g = 0; g < 4; ++g)
                acc[g] = __builtin_amdgcn_mfma_f32_16x16x32_f16(
                    __builtin_bit_cast(f16x8, af[g][kt]), bf, acc[g], 0, 0, 0);
        }
        float h[4];
        #pragma unroll
        for (int r = 0; r < 4; ++r) {
            float ai = fast_sigmoid(acc[0][r]);
            float afg = fast_sigmoid(acc[1][r]);
            float ag = fast_tanh(acc[2][r]);
            float ao = fast_sigmoid(acc[3][r]);
            c[r] = fmaf(afg, c[r], ai * ag);
            h[r] = ao * fast_tanh(c[r]);
        }
        uint2 hp = make_uint2(pack_f16(h[0], h[1]), pack_f16(h[2], h[3]));
        *reinterpret_cast<uint2*>(&XT[nxt][l15][64 + jb]) = hp;
        float4 hv = make_float4(h[0], h[1], h[2], h[3]);
        *reinterpret_cast<float4*>(
            r2 + ((size_t)(b0b + l15) * TT + m) * 128 + jb) = hv;
        if (m + 1 < TT)
            *reinterpret_cast<unsigned*>(&XT[nxt][sc][2 * su]) = rn;
        __syncthreads();
    }
}

// out[bt] = tanh(dot(r2[bt,:128], Wl) + bl)
__global__ __launch_bounds__(256) void final_proj(
    const float* __restrict__ r,   // [B*T, 128]
    const float* __restrict__ Wl,  // [128]
    const float* __restrict__ bl,  // [1]
    float* __restrict__ out)       // [B*T]
{
    __shared__ float wl[128];
    const int tid = threadIdx.x;
    if (tid < 128) wl[tid] = Wl[tid];
    __syncthreads();

    const int bt = blockIdx.x * 256 + tid;
    const float4* rr = reinterpret_cast<const float4*>(r + (size_t)bt * 128);
    float a0 = 0.f, a1 = 0.f, a2 = 0.f, a3 = 0.f;
    #pragma unroll
    for (int k = 0; k < 32; ++k) {
        float4 v = rr[k];
        a0 = fmaf(v.x, wl[4 * k + 0], a0);
        a1 = fmaf(v.y, wl[4 * k + 1], a1);
        a2 = fmaf(v.z, wl[4 * k + 2], a2);
        a3 = fmaf(v.w, wl[4 * k + 3], a3);
    }
    out[bt] = tanhf(((a0 + a1) + (a2 + a3)) + bl[0]);
}

extern "C" void kernel_launch(void* const* d_in, const int* in_sizes, int n_in,
                              void* d_out, int out_size, void* d_ws, size_t ws_size,
                              hipStream_t stream) {
    const float* input = (const float*)d_in[0];
    const float* h_0   = (const float*)d_in[1];
    const float* c_0   = (const float*)d_in[2];
    const float* Wih0  = (const float*)d_in[3];
    const float* Whh0  = (const float*)d_in[4];
    const float* b0    = (const float*)d_in[5];
    const float* Wih1  = (const float*)d_in[6];
    const float* Whh1  = (const float*)d_in[7];
    const float* b1    = (const float*)d_in[8];
    const float* Wih2  = (const float*)d_in[9];
    const float* Whh2  = (const float*)d_in[10];
    const float* b2    = (const float*)d_in[11];
    const float* Wl    = (const float*)d_in[12];
    const float* bl    = (const float*)d_in[13];

    float* out = (float*)d_out;                 // [B*T] head output
    float* r2  = out + (size_t)BB * TT;         // [B,T,128] second output

    char* ws = (char*)d_ws;
    unsigned*  r1u  = (unsigned*)ws;                       // 33,554,432 B
    _Float16*  wfC  = (_Float16*)(ws + 33554432);          //    196,608 B
    _Float16*  wfA0 = (_Float16*)(ws + 33751040);          //     40,960 B
    _Float16*  wfA1 = (_Float16*)(ws + 33792000);          //     49,152 B

    hipLaunchKernelGGL(reorder_wf, dim3(560), dim3(256), 0, stream,
                       Wih0, Whh0, Wih1, Whh1, Wih2, Whh2, wfA0, wfA1, wfC);
    hipLaunchKernelGGL(lstm01_mfma, dim3(NBLK), dim3(512), 0, stream,
                       input, wfA0, wfA1, b0, b1, h_0, c_0, r1u);
    hipLaunchKernelGGL(lstm2_mfma, dim3(NBLK), dim3(512), 0, stream,
                       r1u, wfC, b2, r2);
    hipLaunchKernelGGL(final_proj, dim3(BB * TT / 256), dim3(256), 0, stream,
                       r2, Wl, bl, out);
}